// Round 6
// baseline (42.090 us; speedup 1.0000x reference)
//
#include <hip/hip_runtime.h>
#include <hip/hip_bf16.h>
#include <cstdint>
#include <cstddef>

#define VOCAB   32000
#define HIDDEN  1024
#define BATCH   128
#define SEQ     2048
#define NEG_INF -1.0e9f

#define BN 128
#define BK 64
#define NT 8      // N tiles (1024/128)
#define KG 32     // split-K groups -> 256 blocks = 1/CU exactly

#define QSPLIT 4
#define QV (VOCAB / QSPLIT)   // 8000 vocab entries per A-sub-block

typedef __attribute__((ext_vector_type(8))) short  short8;
typedef __attribute__((ext_vector_type(4))) float  f32x4;

union BF2 { __hip_bfloat162 h; uint32_t u; };
static __device__ __forceinline__ uint32_t pk2(float lo, float hi) {
  BF2 c; c.h = __float22bfloat162_rn(make_float2(lo, hi));  // v_cvt_pk_bf16_f32
  return c.u;
}
union S8U4 { short8 s; uint32_t u[4]; };
static __device__ __forceinline__ short8 pack8(const float* f) {
  S8U4 r;
  r.u[0] = pk2(f[0], f[1]); r.u[1] = pk2(f[2], f[3]);
  r.u[2] = pk2(f[4], f[5]); r.u[3] = pk2(f[6], f[7]);
  return r.s;
}
static __device__ __forceinline__ float bf2f(ushort u) {
  return __uint_as_float(((uint32_t)u) << 16);
}

typedef const uint32_t __attribute__((address_space(1))) gu32;
typedef uint32_t       __attribute__((address_space(3))) lu32;
static __device__ __forceinline__ void g2lds16(const void* g, void* l) {
  __builtin_amdgcn_global_load_lds((gu32*)g, (lu32*)l, 16, 0, 0);
}

// Raw barrier keeping N VMEM instrs in flight (T4: counted vmcnt, no drain).
#define PIPE_BARRIER(N) do {                                         \
    __builtin_amdgcn_sched_barrier(0);                               \
    asm volatile("s_waitcnt vmcnt(" #N ") lgkmcnt(0)" ::: "memory"); \
    __builtin_amdgcn_sched_barrier(0);                               \
    __builtin_amdgcn_s_barrier();                                    \
    __builtin_amdgcn_sched_barrier(0);                               \
  } while (0)

// ---------------------------------------------------------------------------
// Kernel A (vocab-split x4): block (b,q) computes the full masked softmax for
// row b (redundant x4, cheap) but scatters only tokens in its vocab quarter
// into a 32 KB LDS accumulator, then writes its quarter of pooled_bf as bf16.
// 512 blocks -> 2x CU coverage, 4x smaller LDS zero, same HBM traffic.
// ---------------------------------------------------------------------------
__global__ __launch_bounds__(512) void softmax_scatter_q(
    const int* __restrict__ x, const float* __restrict__ w_attn,
    const float* __restrict__ b_attn, ushort* __restrict__ pooled_bf) {
  extern __shared__ float lds[];          // QV floats = 32 KB
  const int b   = blockIdx.x >> 2;
  const int q   = blockIdx.x & 3;
  const int tid = threadIdx.x;
  const int vlo = q * QV, vhi = vlo + QV;

  float4* l4 = (float4*)lds;
#pragma unroll
  for (int i = 0; i < QV / 4 / 512 + 1; ++i) {
    const int idx = tid + i * 512;
    if (idx < QV / 4) l4[idx] = (float4){0.f, 0.f, 0.f, 0.f};
  }

  const int* xr = x + (size_t)b * SEQ;
  const float ba = b_attn[0];
  int xi[4]; float lg[4];
  float m = -3.0e38f;
#pragma unroll
  for (int i = 0; i < 4; ++i) {
    int t = xr[tid + 512 * i];
    xi[i] = t;
    float v = (t > 0) ? (w_attn[t] + ba) : NEG_INF;
    lg[i] = v;
    m = fmaxf(m, v);
  }
#pragma unroll
  for (int off = 32; off; off >>= 1) m = fmaxf(m, __shfl_xor(m, off));
  __shared__ float red[8], red2[8];
  if ((tid & 63) == 0) red[tid >> 6] = m;
  __syncthreads();                        // also orders zero-loop vs atomics
  float M = red[0];
#pragma unroll
  for (int i = 1; i < 8; ++i) M = fmaxf(M, red[i]);

  float e[4], s = 0.f;
#pragma unroll
  for (int i = 0; i < 4; ++i) {
    float v = (xi[i] > 0) ? __expf(lg[i] - M) : 0.f;
    e[i] = v; s += v;
  }
#pragma unroll
  for (int off = 32; off; off >>= 1) s += __shfl_xor(s, off);
  if ((tid & 63) == 0) red2[tid >> 6] = s;
  __syncthreads();
  float S = 0.f;
#pragma unroll
  for (int i = 0; i < 8; ++i) S += red2[i];
  const float inv = 1.0f / S;
#pragma unroll
  for (int i = 0; i < 4; ++i)
    if (xi[i] >= (vlo > 0 ? vlo : 1) && xi[i] < vhi)
      atomicAdd(&lds[xi[i] - vlo], e[i] * inv);   // ds_add_f32
  __syncthreads();

  ushort* pr = pooled_bf + (size_t)b * VOCAB + vlo;
#pragma unroll
  for (int i = 0; i < QV / 4 / 512 + 1; ++i) {
    const int idx = tid + i * 512;
    if (idx < QV / 4) {
      float4 v = l4[idx];
      uint2 o = {pk2(v.x, v.y), pk2(v.z, v.w)};
      *(uint2*)(pr + idx * 4) = o;
    }
  }
}

// ---------------------------------------------------------------------------
// Kernel B: split-K bf16 MFMA GEMM, 128x128x64 tiles, 8 waves (2m x 4n),
// fully global_load_lds-staged, ring-3 LDS buffers, 2-tile-deep pipeline
// with counted vmcnt(6) + raw s_barrier. B issued before A (B needs HBM
// latency cover; A is mostly L2-hot). (verified structure from R5)
// ---------------------------------------------------------------------------
template <bool ATOMIC>
__global__ __launch_bounds__(512, 2) void gemm_kernel(
    const ushort* __restrict__ pooled_bf, const float* __restrict__ w1,
    void* __restrict__ hout_v) {
  extern __shared__ char smem[];
  ushort* As = (ushort*)smem;                       // 3 x [128][64] bf16
  float*  Bs = (float*)(smem + 3 * 16384);          // 3 x [64][128] f32

  const int tid  = threadIdx.x;
  const int lane = tid & 63;
  const int wid  = tid >> 6;
  // XCD swizzle: XCD x owns g in [x*4, x*4+4), all nt (pooled slice L2-local)
  const int id2 = (blockIdx.x & 7) * 32 + (blockIdx.x >> 3);
  const int nt  = id2 & 7;
  const int g   = id2 >> 3;
  const int n0  = nt * BN;

  int kb, ke;                       // 500 K-tiles: 20 groups of 16, 12 of 15
  if (g < 20) { kb = g * 16;              ke = kb + 16; }
  else        { kb = 320 + (g - 20) * 15; ke = kb + 15; }

  const int wm = wid >> 2, wn = wid & 3;            // 2x4 waves, 64x32 each
  const int fr = lane & 15, fq = lane >> 4;

  f32x4 acc[4][2];
#pragma unroll
  for (int i = 0; i < 4; ++i)
#pragma unroll
    for (int j = 0; j < 2; ++j) acc[i][j] = (f32x4){0.f, 0.f, 0.f, 0.f};

  // A issue: per wave 2 granules (1KB = 8 rows); source oct pre-swizzled
  const char* pbase = (const char*)pooled_bf;
  int aoff[2];
#pragma unroll
  for (int i = 0; i < 2; ++i) {
    const int row = (wid * 2 + i) * 8 + (lane >> 3);
    const int oct = (lane & 7) ^ (lane >> 3);
    aoff[i] = row * (VOCAB * 2) + oct * 16;         // bytes
  }
  // B issue: per wave 4 granules (1KB = 2 k-rows); n-granule pre-swizzled
  int bkl[4], bsn[4];
#pragma unroll
  for (int i = 0; i < 4; ++i) {
    const int kl = (wid * 4 + i) * 2 + (lane >> 5);
    bkl[i] = kl;
    bsn[i] = ((lane & 31) ^ ((kl >> 1) & 7)) * 4;   // logical n offset
  }

  auto issueA = [&](int kt, int buf) {
    char* dst = (char*)As + buf * 16384;
#pragma unroll
    for (int i = 0; i < 2; ++i)
      g2lds16(pbase + aoff[i] + kt * (BK * 2), dst + (wid * 2 + i) * 1024);
  };
  auto issueB = [&](int kt, int buf) {
    char* dst = (char*)Bs + buf * 32768;
#pragma unroll
    for (int i = 0; i < 4; ++i)
      g2lds16(w1 + (size_t)(kt * BK + bkl[i]) * HIDDEN + n0 + bsn[i],
              dst + (wid * 4 + i) * 1024);
  };
  auto compute = [&](int buf) {
    const ushort* Ab = As + buf * 8192;
    const char*   Bb = (const char*)(Bs + buf * 8192);
    short8 af[2][4], bfr[2][2];
#pragma unroll
    for (int ks = 0; ks < 2; ++ks) {
      const int osw = ((ks * 4 + fq) ^ (fr & 7)) << 3;
#pragma unroll
      for (int mi = 0; mi < 4; ++mi) {
        const int row = wm * 64 + mi * 16 + fr;
        af[ks][mi] = *(const short8*)(Ab + row * 64 + osw);
      }
    }
#pragma unroll
    for (int ni = 0; ni < 2; ++ni) {
      const int n  = wn * 32 + ni * 16 + fr;
      const int nb = ((n >> 2) << 4) | ((n & 3) << 2);
#pragma unroll
      for (int ks = 0; ks < 2; ++ks) {
        float f[8];
#pragma unroll
        for (int jp = 0; jp < 4; ++jp) {
          const int kl  = ks * 32 + fq * 8 + jp * 2;
          const int sw4 = ((kl >> 1) & 7) << 4;
          const char* p = Bb + kl * 512 + (nb ^ sw4);
          f[jp * 2]     = *(const float*)p;          // ds_read2_b32 pair
          f[jp * 2 + 1] = *(const float*)(p + 512);
        }
        bfr[ks][ni] = pack8(f);
      }
    }
#pragma unroll
    for (int ks = 0; ks < 2; ++ks)
#pragma unroll
      for (int mi = 0; mi < 4; ++mi)
#pragma unroll
        for (int ni = 0; ni < 2; ++ni)
          acc[mi][ni] = __builtin_amdgcn_mfma_f32_16x16x32_bf16(
              af[ks][mi], bfr[ks][ni], acc[mi][ni], 0, 0, 0);
  };

  // prologue: 2 tiles issued (12 VMEM/wave); retire tile kb's 6
  issueB(kb, 0);     issueA(kb, 0);
  issueB(kb + 1, 1); issueA(kb + 1, 1);
  PIPE_BARRIER(6);

  int cu = 0, is = 2;
  for (int kt = kb; kt + 2 < ke; ++kt) {
    issueB(kt + 2, is); issueA(kt + 2, is);   // 6 VMEM, in flight 2 iters
    compute(cu);
    PIPE_BARRIER(6);                          // retire tile kt+1, keep kt+2
    cu = (cu == 2) ? 0 : cu + 1;
    is = (is == 2) ? 0 : is + 1;
  }
  compute(cu);                                // tile ke-2
  cu = (cu == 2) ? 0 : cu + 1;
  PIPE_BARRIER(0);                            // drain tile ke-1's loads
  compute(cu);                                // tile ke-1

  // epilogue: C/D mapping col = lane&15, row = (lane>>4)*4 + r  [m89-verified]
#pragma unroll
  for (int mi = 0; mi < 4; ++mi) {
#pragma unroll
    for (int ni = 0; ni < 2; ++ni) {
      const int col = n0 + wn * 32 + ni * 16 + fr;
#pragma unroll
      for (int r = 0; r < 4; ++r) {
        const int row = wm * 64 + mi * 16 + fq * 4 + r;
        if (ATOMIC) {
          atomicAdd((float*)hout_v + (size_t)row * HIDDEN + col,
                    acc[mi][ni][r]);
        } else {
          union { ushort u; __hip_bfloat16 b; } cv;
          cv.b = __float2bfloat16(acc[mi][ni][r]);
          ((ushort*)hout_v)[((size_t)g * BATCH + row) * HIDDEN + col] = cv.u;
        }
      }
    }
  }
}

// ---------------------------------------------------------------------------
// Kernel C: h = relu(sum_p parts + b1); out = log_softmax(h @ w2 + b2)
// ---------------------------------------------------------------------------
__global__ __launch_bounds__(512) void finalize_kernel(
    const ushort* __restrict__ parts, const float* __restrict__ b1,
    const float* __restrict__ w2, const float* __restrict__ b2,
    float* __restrict__ out) {
  const int b = blockIdx.x, tid = threadIdx.x;
  const int jq = tid & 127;     // j block of 8
  const int ph = tid >> 7;      // p quarter (8 each, KG=32)
  float h[8] = {0.f, 0.f, 0.f, 0.f, 0.f, 0.f, 0.f, 0.f};
  const ushort* src =
      parts + ((size_t)(ph * 8) * BATCH + b) * HIDDEN + jq * 8;
#pragma unroll
  for (int p = 0; p < 8; ++p) {
    short8 v = *(const short8*)(src + (size_t)p * BATCH * HIDDEN);
#pragma unroll
    for (int e = 0; e < 8; ++e) h[e] += bf2f((ushort)v[e]);
  }
  __shared__ float hp[4][HIDDEN];
  *(f32x4*)&hp[ph][jq * 8]     = (f32x4){h[0], h[1], h[2], h[3]};
  *(f32x4*)&hp[ph][jq * 8 + 4] = (f32x4){h[4], h[5], h[6], h[7]};
  __syncthreads();

  float s0 = 0.f, s1 = 0.f;
#pragma unroll
  for (int r = 0; r < 2; ++r) {
    const int j = tid * 2 + r;
    float hv = hp[0][j] + hp[1][j] + hp[2][j] + hp[3][j] + b1[j];
    hv = fmaxf(hv, 0.f);
    float2 w = *(const float2*)(w2 + 2 * j);
    s0 += hv * w.x;
    s1 += hv * w.y;
  }
#pragma unroll
  for (int off = 32; off; off >>= 1) {
    s0 += __shfl_xor(s0, off);
    s1 += __shfl_xor(s1, off);
  }
  __shared__ float r0[8], r1[8];
  if ((tid & 63) == 0) { r0[tid >> 6] = s0; r1[tid >> 6] = s1; }
  __syncthreads();
  if (tid == 0) {
    float l0 = b2[0], l1 = b2[1];
#pragma unroll
    for (int i = 0; i < 8; ++i) { l0 += r0[i]; l1 += r1[i]; }
    float mx = fmaxf(l0, l1);
    float lse = mx + logf(__expf(l0 - mx) + __expf(l1 - mx));
    out[2 * b]     = l0 - lse;
    out[2 * b + 1] = l1 - lse;
  }
}

// f32 fallback finalize (small-ws atomic path)
__global__ __launch_bounds__(256) void finalize_f32_kernel(
    const float* __restrict__ hbuf, const float* __restrict__ b1,
    const float* __restrict__ w2, const float* __restrict__ b2,
    float* __restrict__ out) {
  const int b = blockIdx.x, tid = threadIdx.x;
  const int j0 = tid * 4;
  float4 h = *(const float4*)(hbuf + ((size_t)b << 10) + j0);
  float hv0 = fmaxf(h.x + b1[j0 + 0], 0.f);
  float hv1 = fmaxf(h.y + b1[j0 + 1], 0.f);
  float hv2 = fmaxf(h.z + b1[j0 + 2], 0.f);
  float hv3 = fmaxf(h.w + b1[j0 + 3], 0.f);
  float4 wa = *(const float4*)(w2 + 2 * j0);
  float4 wb = *(const float4*)(w2 + 2 * j0 + 4);
  float s0 = hv0 * wa.x + hv1 * wa.z + hv2 * wb.x + hv3 * wb.z;
  float s1 = hv0 * wa.y + hv1 * wa.w + hv2 * wb.y + hv3 * wb.w;
#pragma unroll
  for (int off = 32; off; off >>= 1) {
    s0 += __shfl_xor(s0, off);
    s1 += __shfl_xor(s1, off);
  }
  __shared__ float r0[4], r1[4];
  if ((tid & 63) == 0) { r0[tid >> 6] = s0; r1[tid >> 6] = s1; }
  __syncthreads();
  if (tid == 0) {
    float l0 = r0[0] + r0[1] + r0[2] + r0[3] + b2[0];
    float l1 = r1[0] + r1[1] + r1[2] + r1[3] + b2[1];
    float mx = fmaxf(l0, l1);
    float lse = mx + logf(__expf(l0 - mx) + __expf(l1 - mx));
    out[2 * b]     = l0 - lse;
    out[2 * b + 1] = l1 - lse;
  }
}

__global__ __launch_bounds__(256) void zero_kernel(float4* __restrict__ p,
                                                   int n4) {
  int i = blockIdx.x * 256 + threadIdx.x;
  const int stride = gridDim.x * 256;
  for (; i < n4; i += stride) p[i] = (float4){0.f, 0.f, 0.f, 0.f};
}

// ---------------------------------------------------------------------------
extern "C" void kernel_launch(void* const* d_in, const int* in_sizes, int n_in,
                              void* d_out, int out_size, void* d_ws,
                              size_t ws_size, hipStream_t stream) {
  const int*   x      = (const int*)  d_in[0];
  const float* w_attn = (const float*)d_in[1];
  const float* b_attn = (const float*)d_in[2];
  const float* w1     = (const float*)d_in[3];
  const float* b1     = (const float*)d_in[4];
  const float* w2     = (const float*)d_in[5];
  const float* b2     = (const float*)d_in[6];
  float* out = (float*)d_out;

  const size_t pbfBytes  = (size_t)BATCH * VOCAB * sizeof(ushort);        // 8.19 MB
  const size_t partBytes = (size_t)KG * BATCH * HIDDEN * sizeof(ushort);  // 8.39 MB
  const int    ldsA      = QV * sizeof(float);                            // 32 KB
  const int    ldsG      = 3 * 16384 + 3 * 32768;                         // 144 KB

  ushort* pooled_bf = (ushort*)d_ws;
  ushort* parts     = (ushort*)((char*)d_ws + pbfBytes);

  if (ws_size >= pbfBytes + partBytes) {
    softmax_scatter_q<<<BATCH * QSPLIT, 512, ldsA, stream>>>(x, w_attn,
                                                             b_attn, pooled_bf);
    gemm_kernel<false><<<NT * KG, 512, ldsG, stream>>>(pooled_bf, w1, parts);
    finalize_kernel<<<BATCH, 512, 0, stream>>>(parts, b1, w2, b2, out);
  } else {
    float* hbuf = (float*)((char*)d_ws + pbfBytes);
    const size_t hBytes = (size_t)BATCH * HIDDEN * sizeof(float);
    zero_kernel<<<256, 256, 0, stream>>>((float4*)hbuf, (int)(hBytes / 16));
    softmax_scatter_q<<<BATCH * QSPLIT, 512, ldsA, stream>>>(x, w_attn,
                                                             b_attn, pooled_bf);
    gemm_kernel<true><<<NT * KG, 512, ldsG, stream>>>(pooled_bf, w1, hbuf);
    finalize_f32_kernel<<<BATCH, 256, 0, stream>>>(hbuf, b1, w2, b2, out);
  }
}

// Round 7
// 40.161 us; speedup vs baseline: 1.0480x; 1.0480x over previous
//
#include <hip/hip_runtime.h>
#include <hip/hip_bf16.h>
#include <cstdint>
#include <cstddef>

#define VOCAB   32000
#define HIDDEN  1024
#define BATCH   128
#define SEQ     2048
#define NEG_INF -1.0e9f

#define BN 128
#define BK 64
#define NT 8      // N tiles (1024/128)
#define KG 32     // split-K groups -> 256 blocks = 1/CU exactly

#define QSPLIT 2
#define QV (VOCAB / QSPLIT)   // 16000 vocab entries per A-sub-block (64 KB LDS)

typedef __attribute__((ext_vector_type(8))) short  short8;
typedef __attribute__((ext_vector_type(4))) float  f32x4;

union BF2 { __hip_bfloat162 h; uint32_t u; };
static __device__ __forceinline__ uint32_t pk2(float lo, float hi) {
  BF2 c; c.h = __float22bfloat162_rn(make_float2(lo, hi));  // v_cvt_pk_bf16_f32
  return c.u;
}
union S8U4 { short8 s; uint32_t u[4]; };
static __device__ __forceinline__ short8 pack8(const float* f) {
  S8U4 r;
  r.u[0] = pk2(f[0], f[1]); r.u[1] = pk2(f[2], f[3]);
  r.u[2] = pk2(f[4], f[5]); r.u[3] = pk2(f[6], f[7]);
  return r.s;
}
static __device__ __forceinline__ float bf2f(ushort u) {
  return __uint_as_float(((uint32_t)u) << 16);
}

typedef const uint32_t __attribute__((address_space(1))) gu32;
typedef uint32_t       __attribute__((address_space(3))) lu32;
static __device__ __forceinline__ void g2lds16(const void* g, void* l) {
  __builtin_amdgcn_global_load_lds((gu32*)g, (lu32*)l, 16, 0, 0);
}

// Raw barrier keeping N VMEM instrs in flight (T4: counted vmcnt, no drain).
#define PIPE_BARRIER(N) do {                                         \
    __builtin_amdgcn_sched_barrier(0);                               \
    asm volatile("s_waitcnt vmcnt(" #N ") lgkmcnt(0)" ::: "memory"); \
    __builtin_amdgcn_sched_barrier(0);                               \
    __builtin_amdgcn_s_barrier();                                    \
    __builtin_amdgcn_sched_barrier(0);                               \
  } while (0)

// ---------------------------------------------------------------------------
// Kernel A (half-split, R7): block (b,q) runs the FULL row softmax with 1024
// threads (2 gathers/thread — same serial chain depth as the proven R5 form)
// but scatters only tokens in its vocab half into a 64 KB LDS accumulator and
// writes that half of pooled_bf. 256 blocks -> full CU coverage on writeout;
// redundancy only 2x on L2-hot x / w_attn reads.
// (R6's 4-way split regressed because it DOUBLED the per-thread gather chain.)
// ---------------------------------------------------------------------------
__global__ __launch_bounds__(1024) void softmax_scatter_h(
    const int* __restrict__ x, const float* __restrict__ w_attn,
    const float* __restrict__ b_attn, ushort* __restrict__ pooled_bf) {
  extern __shared__ float lds[];          // QV floats = 64 KB
  const int b   = blockIdx.x >> 1;
  const int q   = blockIdx.x & 1;
  const int tid = threadIdx.x;
  const int vlo = q * QV, vhi = vlo + QV;
  const int vmin = vlo > 0 ? vlo : 1;     // exclude pad token 0

  float4* l4 = (float4*)lds;
#pragma unroll
  for (int i = 0; i < 4; ++i) {
    const int idx = tid + i * 1024;
    if (idx < QV / 4) l4[idx] = (float4){0.f, 0.f, 0.f, 0.f};
  }

  const int* xr = x + (size_t)b * SEQ;
  const float ba = b_attn[0];
  int xi[2]; float lg[2];
  float m = -3.0e38f;
#pragma unroll
  for (int i = 0; i < 2; ++i) {
    int t = xr[tid + 1024 * i];
    xi[i] = t;
    float v = (t > 0) ? (w_attn[t] + ba) : NEG_INF;
    lg[i] = v;
    m = fmaxf(m, v);
  }
#pragma unroll
  for (int off = 32; off; off >>= 1) m = fmaxf(m, __shfl_xor(m, off));
  __shared__ float red[16], red2[16];
  if ((tid & 63) == 0) red[tid >> 6] = m;
  __syncthreads();                        // also orders zero-loop vs atomics
  float M = red[0];
#pragma unroll
  for (int i = 1; i < 16; ++i) M = fmaxf(M, red[i]);

  float e[2], s = 0.f;
#pragma unroll
  for (int i = 0; i < 2; ++i) {
    float v = (xi[i] > 0) ? __expf(lg[i] - M) : 0.f;
    e[i] = v; s += v;
  }
#pragma unroll
  for (int off = 32; off; off >>= 1) s += __shfl_xor(s, off);
  if ((tid & 63) == 0) red2[tid >> 6] = s;
  __syncthreads();
  float S = 0.f;
#pragma unroll
  for (int i = 0; i < 16; ++i) S += red2[i];
  const float inv = 1.0f / S;
#pragma unroll
  for (int i = 0; i < 2; ++i)
    if (xi[i] >= vmin && xi[i] < vhi)
      atomicAdd(&lds[xi[i] - vlo], e[i] * inv);   // ds_add_f32
  __syncthreads();

  ushort* pr = pooled_bf + (size_t)b * VOCAB + vlo;
#pragma unroll
  for (int i = 0; i < 4; ++i) {
    const int idx = tid + i * 1024;
    if (idx < QV / 4) {
      float4 v = l4[idx];
      uint2 o = {pk2(v.x, v.y), pk2(v.z, v.w)};
      *(uint2*)(pr + idx * 4) = o;
    }
  }
}

// ---------------------------------------------------------------------------
// Kernel B: split-K bf16 MFMA GEMM, 128x128x64 tiles, 8 waves (2m x 4n),
// fully global_load_lds-staged, ring-3 LDS buffers, 2-tile-deep pipeline
// with counted vmcnt(6) + raw s_barrier. (verified R5/R6 structure)
// ---------------------------------------------------------------------------
template <bool ATOMIC>
__global__ __launch_bounds__(512, 2) void gemm_kernel(
    const ushort* __restrict__ pooled_bf, const float* __restrict__ w1,
    void* __restrict__ hout_v) {
  extern __shared__ char smem[];
  ushort* As = (ushort*)smem;                       // 3 x [128][64] bf16
  float*  Bs = (float*)(smem + 3 * 16384);          // 3 x [64][128] f32

  const int tid  = threadIdx.x;
  const int lane = tid & 63;
  const int wid  = tid >> 6;
  // XCD swizzle: XCD x owns g in [x*4, x*4+4), all nt (pooled slice L2-local)
  const int id2 = (blockIdx.x & 7) * 32 + (blockIdx.x >> 3);
  const int nt  = id2 & 7;
  const int g   = id2 >> 3;
  const int n0  = nt * BN;

  int kb, ke;                       // 500 K-tiles: 20 groups of 16, 12 of 15
  if (g < 20) { kb = g * 16;              ke = kb + 16; }
  else        { kb = 320 + (g - 20) * 15; ke = kb + 15; }

  const int wm = wid >> 2, wn = wid & 3;            // 2x4 waves, 64x32 each
  const int fr = lane & 15, fq = lane >> 4;

  f32x4 acc[4][2];
#pragma unroll
  for (int i = 0; i < 4; ++i)
#pragma unroll
    for (int j = 0; j < 2; ++j) acc[i][j] = (f32x4){0.f, 0.f, 0.f, 0.f};

  // A issue: per wave 2 granules (1KB = 8 rows); source oct pre-swizzled
  const char* pbase = (const char*)pooled_bf;
  int aoff[2];
#pragma unroll
  for (int i = 0; i < 2; ++i) {
    const int row = (wid * 2 + i) * 8 + (lane >> 3);
    const int oct = (lane & 7) ^ (lane >> 3);
    aoff[i] = row * (VOCAB * 2) + oct * 16;         // bytes
  }
  // B issue: per wave 4 granules (1KB = 2 k-rows); n-granule pre-swizzled
  int bkl[4], bsn[4];
#pragma unroll
  for (int i = 0; i < 4; ++i) {
    const int kl = (wid * 4 + i) * 2 + (lane >> 5);
    bkl[i] = kl;
    bsn[i] = ((lane & 31) ^ ((kl >> 1) & 7)) * 4;   // logical n offset
  }

  auto issueA = [&](int kt, int buf) {
    char* dst = (char*)As + buf * 16384;
#pragma unroll
    for (int i = 0; i < 2; ++i)
      g2lds16(pbase + aoff[i] + kt * (BK * 2), dst + (wid * 2 + i) * 1024);
  };
  auto issueB = [&](int kt, int buf) {
    char* dst = (char*)Bs + buf * 32768;
#pragma unroll
    for (int i = 0; i < 4; ++i)
      g2lds16(w1 + (size_t)(kt * BK + bkl[i]) * HIDDEN + n0 + bsn[i],
              dst + (wid * 4 + i) * 1024);
  };
  auto compute = [&](int buf) {
    const ushort* Ab = As + buf * 8192;
    const char*   Bb = (const char*)(Bs + buf * 8192);
    short8 af[2][4], bfr[2][2];
#pragma unroll
    for (int ks = 0; ks < 2; ++ks) {
      const int osw = ((ks * 4 + fq) ^ (fr & 7)) << 3;
#pragma unroll
      for (int mi = 0; mi < 4; ++mi) {
        const int row = wm * 64 + mi * 16 + fr;
        af[ks][mi] = *(const short8*)(Ab + row * 64 + osw);
      }
    }
#pragma unroll
    for (int ni = 0; ni < 2; ++ni) {
      const int n  = wn * 32 + ni * 16 + fr;
      const int nb = ((n >> 2) << 4) | ((n & 3) << 2);
#pragma unroll
      for (int ks = 0; ks < 2; ++ks) {
        float f[8];
#pragma unroll
        for (int jp = 0; jp < 4; ++jp) {
          const int kl  = ks * 32 + fq * 8 + jp * 2;
          const int sw4 = ((kl >> 1) & 7) << 4;
          const char* p = Bb + kl * 512 + (nb ^ sw4);
          f[jp * 2]     = *(const float*)p;          // ds_read2_b32 pair
          f[jp * 2 + 1] = *(const float*)(p + 512);
        }
        bfr[ks][ni] = pack8(f);
      }
    }
#pragma unroll
    for (int ks = 0; ks < 2; ++ks)
#pragma unroll
      for (int mi = 0; mi < 4; ++mi)
#pragma unroll
        for (int ni = 0; ni < 2; ++ni)
          acc[mi][ni] = __builtin_amdgcn_mfma_f32_16x16x32_bf16(
              af[ks][mi], bfr[ks][ni], acc[mi][ni], 0, 0, 0);
  };

  // prologue: 2 tiles issued (12 VMEM/wave); retire tile kb's 6
  issueB(kb, 0);     issueA(kb, 0);
  issueB(kb + 1, 1); issueA(kb + 1, 1);
  PIPE_BARRIER(6);

  int cu = 0, is = 2;
  for (int kt = kb; kt + 2 < ke; ++kt) {
    issueB(kt + 2, is); issueA(kt + 2, is);   // 6 VMEM, in flight 2 iters
    compute(cu);
    PIPE_BARRIER(6);                          // retire tile kt+1, keep kt+2
    cu = (cu == 2) ? 0 : cu + 1;
    is = (is == 2) ? 0 : is + 1;
  }
  compute(cu);                                // tile ke-2
  cu = (cu == 2) ? 0 : cu + 1;
  PIPE_BARRIER(0);                            // drain tile ke-1's loads
  compute(cu);                                // tile ke-1

  // epilogue: C/D mapping col = lane&15, row = (lane>>4)*4 + r  [m89-verified]
#pragma unroll
  for (int mi = 0; mi < 4; ++mi) {
#pragma unroll
    for (int ni = 0; ni < 2; ++ni) {
      const int col = n0 + wn * 32 + ni * 16 + fr;
#pragma unroll
      for (int r = 0; r < 4; ++r) {
        const int row = wm * 64 + mi * 16 + fq * 4 + r;
        if (ATOMIC) {
          atomicAdd((float*)hout_v + (size_t)row * HIDDEN + col,
                    acc[mi][ni][r]);
        } else {
          union { ushort u; __hip_bfloat16 b; } cv;
          cv.b = __float2bfloat16(acc[mi][ni][r]);
          ((ushort*)hout_v)[((size_t)g * BATCH + row) * HIDDEN + col] = cv.u;
        }
      }
    }
  }
}

// ---------------------------------------------------------------------------
// Kernel C: h = relu(sum_p parts + b1); out = log_softmax(h @ w2 + b2)
// ---------------------------------------------------------------------------
__global__ __launch_bounds__(512) void finalize_kernel(
    const ushort* __restrict__ parts, const float* __restrict__ b1,
    const float* __restrict__ w2, const float* __restrict__ b2,
    float* __restrict__ out) {
  const int b = blockIdx.x, tid = threadIdx.x;
  const int jq = tid & 127;     // j block of 8
  const int ph = tid >> 7;      // p quarter (8 each, KG=32)
  float h[8] = {0.f, 0.f, 0.f, 0.f, 0.f, 0.f, 0.f, 0.f};
  const ushort* src =
      parts + ((size_t)(ph * 8) * BATCH + b) * HIDDEN + jq * 8;
#pragma unroll
  for (int p = 0; p < 8; ++p) {
    short8 v = *(const short8*)(src + (size_t)p * BATCH * HIDDEN);
#pragma unroll
    for (int e = 0; e < 8; ++e) h[e] += bf2f((ushort)v[e]);
  }
  __shared__ float hp[4][HIDDEN];
  *(f32x4*)&hp[ph][jq * 8]     = (f32x4){h[0], h[1], h[2], h[3]};
  *(f32x4*)&hp[ph][jq * 8 + 4] = (f32x4){h[4], h[5], h[6], h[7]};
  __syncthreads();

  float s0 = 0.f, s1 = 0.f;
#pragma unroll
  for (int r = 0; r < 2; ++r) {
    const int j = tid * 2 + r;
    float hv = hp[0][j] + hp[1][j] + hp[2][j] + hp[3][j] + b1[j];
    hv = fmaxf(hv, 0.f);
    float2 w = *(const float2*)(w2 + 2 * j);
    s0 += hv * w.x;
    s1 += hv * w.y;
  }
#pragma unroll
  for (int off = 32; off; off >>= 1) {
    s0 += __shfl_xor(s0, off);
    s1 += __shfl_xor(s1, off);
  }
  __shared__ float r0[8], r1[8];
  if ((tid & 63) == 0) { r0[tid >> 6] = s0; r1[tid >> 6] = s1; }
  __syncthreads();
  if (tid == 0) {
    float l0 = b2[0], l1 = b2[1];
#pragma unroll
    for (int i = 0; i < 8; ++i) { l0 += r0[i]; l1 += r1[i]; }
    float mx = fmaxf(l0, l1);
    float lse = mx + logf(__expf(l0 - mx) + __expf(l1 - mx));
    out[2 * b]     = l0 - lse;
    out[2 * b + 1] = l1 - lse;
  }
}

// f32 fallback finalize (small-ws atomic path)
__global__ __launch_bounds__(256) void finalize_f32_kernel(
    const float* __restrict__ hbuf, const float* __restrict__ b1,
    const float* __restrict__ w2, const float* __restrict__ b2,
    float* __restrict__ out) {
  const int b = blockIdx.x, tid = threadIdx.x;
  const int j0 = tid * 4;
  float4 h = *(const float4*)(hbuf + ((size_t)b << 10) + j0);
  float hv0 = fmaxf(h.x + b1[j0 + 0], 0.f);
  float hv1 = fmaxf(h.y + b1[j0 + 1], 0.f);
  float hv2 = fmaxf(h.z + b1[j0 + 2], 0.f);
  float hv3 = fmaxf(h.w + b1[j0 + 3], 0.f);
  float4 wa = *(const float4*)(w2 + 2 * j0);
  float4 wb = *(const float4*)(w2 + 2 * j0 + 4);
  float s0 = hv0 * wa.x + hv1 * wa.z + hv2 * wb.x + hv3 * wb.z;
  float s1 = hv0 * wa.y + hv1 * wa.w + hv2 * wb.y + hv3 * wb.w;
#pragma unroll
  for (int off = 32; off; off >>= 1) {
    s0 += __shfl_xor(s0, off);
    s1 += __shfl_xor(s1, off);
  }
  __shared__ float r0[4], r1[4];
  if ((tid & 63) == 0) { r0[tid >> 6] = s0; r1[tid >> 6] = s1; }
  __syncthreads();
  if (tid == 0) {
    float l0 = r0[0] + r0[1] + r0[2] + r0[3] + b2[0];
    float l1 = r1[0] + r1[1] + r1[2] + r1[3] + b2[1];
    float mx = fmaxf(l0, l1);
    float lse = mx + logf(__expf(l0 - mx) + __expf(l1 - mx));
    out[2 * b]     = l0 - lse;
    out[2 * b + 1] = l1 - lse;
  }
}

__global__ __launch_bounds__(256) void zero_kernel(float4* __restrict__ p,
                                                   int n4) {
  int i = blockIdx.x * 256 + threadIdx.x;
  const int stride = gridDim.x * 256;
  for (; i < n4; i += stride) p[i] = (float4){0.f, 0.f, 0.f, 0.f};
}

// ---------------------------------------------------------------------------
extern "C" void kernel_launch(void* const* d_in, const int* in_sizes, int n_in,
                              void* d_out, int out_size, void* d_ws,
                              size_t ws_size, hipStream_t stream) {
  const int*   x      = (const int*)  d_in[0];
  const float* w_attn = (const float*)d_in[1];
  const float* b_attn = (const float*)d_in[2];
  const float* w1     = (const float*)d_in[3];
  const float* b1     = (const float*)d_in[4];
  const float* w2     = (const float*)d_in[5];
  const float* b2     = (const float*)d_in[6];
  float* out = (float*)d_out;

  const size_t pbfBytes  = (size_t)BATCH * VOCAB * sizeof(ushort);        // 8.19 MB
  const size_t partBytes = (size_t)KG * BATCH * HIDDEN * sizeof(ushort);  // 8.39 MB
  const int    ldsA      = QV * sizeof(float);                            // 64 KB
  const int    ldsG      = 3 * 16384 + 3 * 32768;                         // 144 KB

  ushort* pooled_bf = (ushort*)d_ws;
  ushort* parts     = (ushort*)((char*)d_ws + pbfBytes);

  if (ws_size >= pbfBytes + partBytes) {
    softmax_scatter_h<<<BATCH * QSPLIT, 1024, ldsA, stream>>>(x, w_attn,
                                                              b_attn,
                                                              pooled_bf);
    gemm_kernel<false><<<NT * KG, 512, ldsG, stream>>>(pooled_bf, w1, parts);
    finalize_kernel<<<BATCH, 512, 0, stream>>>(parts, b1, w2, b2, out);
  } else {
    float* hbuf = (float*)((char*)d_ws + pbfBytes);
    const size_t hBytes = (size_t)BATCH * HIDDEN * sizeof(float);
    zero_kernel<<<256, 256, 0, stream>>>((float4*)hbuf, (int)(hBytes / 16));
    softmax_scatter_h<<<BATCH * QSPLIT, 1024, ldsA, stream>>>(x, w_attn,
                                                              b_attn,
                                                              pooled_bf);
    gemm_kernel<true><<<NT * KG, 512, ldsG, stream>>>(pooled_bf, w1, hbuf);
    finalize_f32_kernel<<<BATCH, 256, 0, stream>>>(hbuf, b1, w2, b2, out);
  }
}